// Round 1
// 135.284 us; speedup vs baseline: 1.0550x; 1.0550x over previous
//
#include <hip/hip_runtime.h>

// CountSketch: out[b, i_hash[j]] += s_hash[j] * x[b, j]
//   x [16384, 8192] f32 (512 MB), hashes [8192], out [16384, 2048] f32 (128 MB)
//
// v11 = persistent double-buffered pipeline.
//   - 512 blocks (2/CU, 72 KB LDS), each owns rows {p, p+512, ...} (32 rows).
//   - Metadata (meta0 + overflow records + counts) loaded into REGISTERS once
//     per block; steady row loop has NO global loads except the stage DMA and
//     the out stores -> no compiler-inserted vmcnt drains in the loop.
//   - Per row: issue next row's global_load_lds DMA into the other xs buffer
//     BEFORE computing this row; row-top wait is s_waitcnt vmcnt(16) (drains
//     exactly this row's 8 DMAs, leaves next row's 8 + prev stores in flight).
//   - All barriers are raw s_barrier + counted waits (lgkmcnt(0) intra-row);
//     __syncthreads (vmcnt(0) drain) is never used in the main kernel.
//   - Record caps: round1 <= 1024 (4 uint4/thread in regs), rounds2-5 <= 256
//     (1 uint4/thread). p2_build reroutes over-cap entries to the leftover
//     path (total entries = 8192 <= LEFTCAP, always safe). Random hash:
//     n1~760, n2~45, n3~2 -> fast path identical to v10.

typedef unsigned int u32;
typedef unsigned short u16;

constexpr int D_IN  = 8192;
constexpr int D_F   = 2048;
constexpr int BLOCK = 256;
constexpr int SLOTS = 24;
constexpr int RECCAP  = 2048;   // storage layout capacity (unchanged)
constexpr int C1      = 1024;   // round-1 usage cap (preloadable: 4/thread)
constexpr int C25     = 256;    // rounds 2..5 usage cap (1/thread)
constexpr int LEFTCAP = 8192;
constexpr int GRID    = 512;    // 2 blocks/CU * 256 CU

// workspace layout (bytes) — identical to v10
constexpr size_t OFF_CUR     = 0;       // u32[2048] bucket counts
constexpr size_t OFF_NREC    = 8192;    // u32[8] round record counts (1..5 used)
constexpr size_t OFF_LEFTCNT = 8224;    // u32
constexpr size_t OFF_META0   = 8256;    // uint2[2048] round-0 slots (u16 x4)
constexpr size_t OFF_OV      = 24640;   // u16[2048][24] captured entries
constexpr size_t OFF_REC     = 122944;  // uint4[5][2048] overflow records
constexpr size_t OFF_LEFT    = 286784;  // u32[8192] leftovers
constexpr size_t WS_NEED     = 319552;

// ov entry u16: bits 12:0 idx, bit 14 valid, bit 15 sign
// record: uint4(f, e_lo, e_hi, 0) for entries 4r..4r+3 of its bucket
// leftover u32: f<<16 | sign<<13 | idx

#define ASM_VM16 asm volatile("s_waitcnt vmcnt(16)" ::: "memory")
#define ASM_VM8  asm volatile("s_waitcnt vmcnt(8)"  ::: "memory")
#define ASM_DRAIN asm volatile("s_waitcnt vmcnt(0) lgkmcnt(0)" ::: "memory")
#define ASM_LGKM0 asm volatile("s_waitcnt lgkmcnt(0)" ::: "memory")
#define SCHED0 __builtin_amdgcn_sched_barrier(0)
#define RAWBAR __builtin_amdgcn_s_barrier()
// intra-row barrier: LDS writes visible, loads stay in flight
#define LBAR do { ASM_LGKM0; SCHED0; RAWBAR; SCHED0; } while (0)

__global__ __launch_bounds__(BLOCK) void p0_zero(unsigned char* ws)
{
    int i = blockIdx.x * BLOCK + threadIdx.x;
    if (i < D_F) ((u32*)(ws + OFF_CUR))[i] = 0u;
    if (i < 9)   ((u32*)(ws + OFF_NREC))[i] = 0u;   // nrec[8] + leftcnt
}

__global__ __launch_bounds__(BLOCK) void p1_scatter(
    const float* __restrict__ s_hash, const int* __restrict__ i_hash,
    unsigned char* __restrict__ ws)
{
    int j = blockIdx.x * BLOCK + threadIdx.x;
    if (j >= D_IN) return;
    u32 f   = (u32)i_hash[j];
    u32 sgn = __float_as_uint(s_hash[j]) >> 31;
    u32 pos = atomicAdd(&((u32*)(ws + OFF_CUR))[f], 1u);
    if (pos < (u32)SLOTS) {
        ((u16*)(ws + OFF_OV))[f * SLOTS + pos] =
            (u16)((u32)j | 0x4000u | (sgn << 15));
    } else {
        u32 li = atomicAdd((u32*)(ws + OFF_LEFTCNT), 1u);
        if (li < (u32)LEFTCAP)
            ((u32*)(ws + OFF_LEFT))[li] = (f << 16) | (sgn << 13) | (u32)j;
    }
}

__global__ __launch_bounds__(BLOCK) void p2_build(unsigned char* __restrict__ ws)
{
    int f = blockIdx.x * BLOCK + threadIdx.x;
    if (f >= D_F) return;
    u32 cr = ((const u32*)(ws + OFF_CUR))[f];
    u32 c  = cr < (u32)SLOTS ? cr : (u32)SLOTS;
    const u16* o = ((const u16*)(ws + OFF_OV)) + f * SLOTS;
    auto slot = [&](u32 p) -> u32 { return (p < c) ? (u32)o[p] : 0u; };
    ((uint2*)(ws + OFF_META0))[f] =
        make_uint2(slot(0) | (slot(1) << 16), slot(2) | (slot(3) << 16));
    u32* nrec    = (u32*)(ws + OFF_NREC);
    u32* leftcnt = (u32*)(ws + OFF_LEFTCNT);
    u32* left    = (u32*)(ws + OFF_LEFT);
    for (int r = 1; r <= 5; ++r) {
        u32 base = 4u * (u32)r;
        if (c > base) {
            u32 cap = (r == 1) ? (u32)C1 : (u32)C25;
            u32 idx = atomicAdd(&nrec[r], 1u);
            if (idx < cap) {
                uint4* rec = (uint4*)(ws + OFF_REC + (size_t)(r - 1) * RECCAP * 16);
                rec[idx] = make_uint4((u32)f,
                                      slot(base)     | (slot(base + 1) << 16),
                                      slot(base + 2) | (slot(base + 3) << 16), 0u);
            } else {
                // over-cap: reroute this record's valid entries to leftovers
                u32 hi = c < base + 4u ? c : base + 4u;
                for (u32 p = base; p < hi; ++p) {
                    u32 e  = (u32)o[p];
                    u32 li = atomicAdd(leftcnt, 1u);
                    if (li < (u32)LEFTCAP)
                        left[li] = ((u32)f << 16) | ((e >> 15) << 13) | (e & 0x1FFFu);
                }
            }
        }
    }
}

__device__ __forceinline__ float proc4(const float* xs, u32 lo, u32 hi)
{
    u32 es[4] = { lo & 0xFFFFu, lo >> 16, hi & 0xFFFFu, hi >> 16 };
    float s = 0.0f;
    #pragma unroll
    for (int i = 0; i < 4; ++i) {
        u32 e  = es[i];
        u32 xb = __float_as_uint(xs[e & 0x1FFFu]);
        xb ^= (e & 0x8000u) << 16;                 // +-1 as sign-bit flip
        s += (e & 0x4000u) ? __uint_as_float(xb) : 0.0f;
    }
    return s;
}

__device__ __forceinline__ void stage8(const float* src, float* dst, int t)
{
    #pragma unroll
    for (int i = 0; i < D_IN / (BLOCK * 4); ++i) {   // 8 x 16B/lane, lane-linear
        int off = i * (BLOCK * 4) + t * 4;
        __builtin_amdgcn_global_load_lds(
            (const __attribute__((address_space(1))) void*)(src + off),
            (__attribute__((address_space(3))) void*)(dst + off), 16, 0, 0);
    }
}

__global__ __launch_bounds__(BLOCK, 2) void cs_main(
    const float* __restrict__ x, const unsigned char* __restrict__ ws,
    float* __restrict__ out, int batch)
{
    __shared__ float xs[2][D_IN];   // 64 KB double buffer
    __shared__ float spill[D_F];    //  8 KB -> 72 KB total = 2 blocks/CU
    const int t = threadIdx.x;
    const int G = gridDim.x;

    int row = blockIdx.x;

    // ---- prologue: all metadata -> registers, stage first row ----
    uint2 m0[8];
    const uint2* meta0 = (const uint2*)(ws + OFF_META0);
    #pragma unroll
    for (int k = 0; k < 8; ++k) m0[k] = meta0[t + BLOCK * k];

    const uint4* rec = (const uint4*)(ws + OFF_REC);
    uint4 r1v[4];
    #pragma unroll
    for (int q = 0; q < 4; ++q) r1v[q] = rec[0 * RECCAP + t + BLOCK * q];
    uint4 r2 = rec[1 * RECCAP + t];
    uint4 r3 = rec[2 * RECCAP + t];
    uint4 r4 = rec[3 * RECCAP + t];
    uint4 r5 = rec[4 * RECCAP + t];

    const u32* nrecp = (const u32*)(ws + OFF_NREC);
    u32 n1 = nrecp[1], n2 = nrecp[2], n3 = nrecp[3], n4 = nrecp[4], n5 = nrecp[5];
    n1 = n1 < (u32)C1  ? n1 : (u32)C1;
    n2 = n2 < (u32)C25 ? n2 : (u32)C25;
    n3 = n3 < (u32)C25 ? n3 : (u32)C25;
    n4 = n4 < (u32)C25 ? n4 : (u32)C25;
    n5 = n5 < (u32)C25 ? n5 : (u32)C25;
    u32 nl = *(const u32*)(ws + OFF_LEFTCNT);
    if (nl > (u32)LEFTCAP) nl = LEFTCAP;

    #pragma unroll
    for (int k = 0; k < 8; ++k) spill[t + BLOCK * k] = 0.0f;

    if (row < batch) stage8(x + (size_t)row * D_IN, xs[0], t);

    ASM_DRAIN;          // metadata in regs, row0 staged, spill zeroed
    SCHED0; RAWBAR; SCHED0;

    // ---- persistent row loop ----
    int cur = 0;
    bool first = true;
    while (row < batch) {
        const int next = row + G;
        // 1) prefetch next row into the other buffer (loads stay in flight
        //    across this row's entire compute phase)
        if (next < batch) stage8(x + (size_t)next * D_IN, xs[cur ^ 1], t);

        // 2) row-ready wait: drain exactly this row's 8 DMAs.
        //    outstanding (oldest->newest): loads_row(8) | stores_prev(8) | loads_next(8)
        if (!first) {
            if (next < batch) { ASM_VM16; } else { ASM_VM8; }
            SCHED0; RAWBAR; SCHED0;
        }
        first = false;
        const float* xr = xs[cur];

        // 3) round 0: 4 slots per owned bucket -> registers
        float acc[8];
        #pragma unroll
        for (int k = 0; k < 8; ++k) acc[k] = proc4(xr, m0[k].x, m0[k].y);

        // 4) overflow rounds from register-held records (disjoint buckets
        //    within a round; raw barrier + lgkm between rounds)
        if (n1) {
            #pragma unroll
            for (int q = 0; q < 4; ++q) {
                u32 i = (u32)t + (u32)(BLOCK * q);
                if (i < n1) spill[r1v[q].x & 0x7FFu] += proc4(xr, r1v[q].y, r1v[q].z);
            }
            LBAR;
        }
        if (n2) { if ((u32)t < n2) spill[r2.x & 0x7FFu] += proc4(xr, r2.y, r2.z); LBAR; }
        if (n3) { if ((u32)t < n3) spill[r3.x & 0x7FFu] += proc4(xr, r3.y, r3.z); LBAR; }
        if (n4) { if ((u32)t < n4) spill[r4.x & 0x7FFu] += proc4(xr, r4.y, r4.z); LBAR; }
        if (n5) { if ((u32)t < n5) spill[r5.x & 0x7FFu] += proc4(xr, r5.y, r5.z); LBAR; }

        if (nl) {   // adversarial-only (0 for random hash); uniform branch
            const u32* left = (const u32*)(ws + OFF_LEFT);
            for (u32 i = t; i < nl; i += BLOCK) {
                u32 e  = left[i];
                u32 xb = __float_as_uint(xr[e & 0x1FFFu]) ^ ((e & 0x2000u) << 18);
                atomicAdd(&spill[e >> 16], __uint_as_float(xb));
            }
            LBAR;
        }

        // 5) merge + coalesced stores + spill re-zero for next row
        float* orow = out + (size_t)row * D_F;
        #pragma unroll
        for (int k = 0; k < 8; ++k) {
            int f = t + BLOCK * k;
            float v = acc[k] + spill[f];
            orow[f] = v;
            spill[f] = 0.0f;
        }

        // 6) end-of-row: all waves done reading xs[cur] & spill re-zeroed
        //    (raw barrier, prefetch loads stay in flight)
        LBAR;

        cur ^= 1;
        row = next;
    }
}

// Fallback (ws too small): LDS-atomic scatter, known-correct.
__global__ __launch_bounds__(BLOCK) void cs_scatter_nows(
    const float* __restrict__ x, const float* __restrict__ s_hash,
    const int* __restrict__ i_hash, float* __restrict__ out)
{
    __shared__ float acc[D_F];
    const int t = threadIdx.x;
    const int b = blockIdx.x;
    #pragma unroll
    for (int k = 0; k < D_F / BLOCK; ++k) acc[t + BLOCK * k] = 0.0f;
    __syncthreads();
    const float4* xrow = (const float4*)(x + (size_t)b * D_IN);
    const float4* srow = (const float4*)(s_hash);
    const int4*   irow = (const int4*)(i_hash);
    #pragma unroll
    for (int it = 0; it < D_IN / (BLOCK * 4); ++it) {
        const int i4 = it * BLOCK + t;
        float4 xv = xrow[i4]; float4 sv = srow[i4]; int4 iv = irow[i4];
        atomicAdd(&acc[iv.x & 0x7FF], xv.x * sv.x);
        atomicAdd(&acc[iv.y & 0x7FF], xv.y * sv.y);
        atomicAdd(&acc[iv.z & 0x7FF], xv.z * sv.z);
        atomicAdd(&acc[iv.w & 0x7FF], xv.w * sv.w);
    }
    __syncthreads();
    float4* orow = (float4*)(out + (size_t)b * D_F);
    const float4* acc4 = (const float4*)acc;
    #pragma unroll
    for (int k = 0; k < D_F / (BLOCK * 4); ++k) {
        const int i4 = k * BLOCK + t;
        orow[i4] = acc4[i4];
    }
}

extern "C" void kernel_launch(void* const* d_in, const int* in_sizes, int n_in,
                              void* d_out, int out_size, void* d_ws, size_t ws_size,
                              hipStream_t stream)
{
    const float* x      = (const float*)d_in[0];
    const float* s_hash = (const float*)d_in[1];
    const int*   i_hash = (const int*)d_in[2];
    float*       out    = (float*)d_out;
    const int batch = in_sizes[0] / D_IN;

    if (ws_size >= WS_NEED && batch > 0) {
        unsigned char* ws = (unsigned char*)d_ws;
        p0_zero   <<<(D_F + BLOCK - 1) / BLOCK, BLOCK, 0, stream>>>(ws);
        p1_scatter<<<D_IN / BLOCK, BLOCK, 0, stream>>>(s_hash, i_hash, ws);
        p2_build  <<<D_F / BLOCK, BLOCK, 0, stream>>>(ws);
        int grid = batch < GRID ? batch : GRID;
        cs_main   <<<grid, BLOCK, 0, stream>>>(x, ws, out, batch);
    } else {
        cs_scatter_nows<<<batch, BLOCK, 0, stream>>>(x, s_hash, i_hash, out);
    }
}